// Round 1
// baseline (547.698 us; speedup 1.0000x reference)
//
#include <hip/hip_runtime.h>

// Block-circulant conv reduced to GEMM:
//   out[b, p*64+t, r] = sum_{q,s} A[b*1024+r, q*64+s] * w[p, q, (t-s)&63]
// A is the unfold gather of x (computed on the fly), B-tile is a 64x64
// circulant generated from w[p][q][0..63].
//
// Tiling: BM=64 (rows r), BN=64 (one p block), BK=64 (one q block).
// 256 threads, 4x4 micro-tile per thread. fp32 vector FMA.

#define N_BATCH 8
#define IN_CH 256
#define HW 32
#define QB 36   // K blocks
#define PB 8    // N blocks

__global__ __launch_bounds__(256) void bcc_gemm_f32(
    const float* __restrict__ x,     // (8, 256, 32, 32)
    const float* __restrict__ w,     // (8, 36, 64)
    float* __restrict__ out)         // (8, 512, 32, 32)
{
    __shared__ float As[64][68];  // [mm][s]  (+4 pad keeps float4 16B-aligned)
    __shared__ float Ws[64][68];  // [s][t]

    const int tid = threadIdx.x;
    const int tn  = tid & 15;   // -> t  = tn*4 + j
    const int tm  = tid >> 4;   // -> mm = tm*4 + i
    const int p   = blockIdx.x;        // 0..7   (oc block)
    const int m0  = blockIdx.y * 64;   // 0..8191 row tile base
    const int b   = m0 >> 10;
    const int r0  = m0 & 1023;

    const float* xb = x + (size_t)b * (IN_CH * HW * HW);

    float acc[4][4] = {};

    for (int q = 0; q < QB; ++q) {
        // ---- stage A tile: As[mm][s] = unfold-gather, coalesced over s ----
        #pragma unroll
        for (int i = 0; i < 16; ++i) {
            int idx = i * 256 + tid;          // 0..4095
            int s   = idx & 63;
            int mm  = idx >> 6;
            int r   = r0 + mm;
            int flat = r * 2304 + q * 64 + s; // < 2304*1024
            int feat = flat >> 10;
            int loc  = flat & 1023;
            int c    = feat / 9;
            int kk   = feat - c * 9;
            int hi   = (loc >> 5) + (kk / 3) - 1;
            int wi   = (loc & 31) + (kk % 3) - 1;
            float v = 0.0f;
            if ((unsigned)hi < (unsigned)HW && (unsigned)wi < (unsigned)HW)
                v = xb[(c * HW + hi) * HW + wi];
            As[mm][s] = v;
        }
        // ---- stage W circulant tile: Ws[s][t] = w[p][q][(t-s)&63] ----
        const float* wb = w + (p * QB + q) * 64;
        #pragma unroll
        for (int i = 0; i < 16; ++i) {
            int idx = i * 256 + tid;
            int t   = idx & 63;
            int s   = idx >> 6;
            Ws[s][t] = wb[(t - s) & 63];
        }
        __syncthreads();

        // ---- compute: acc[i][j] += A[tm*4+i][s] * Ws[s][tn*4+j] ----
        #pragma unroll
        for (int s0 = 0; s0 < 64; s0 += 4) {
            float4 a4[4], b4[4];
            #pragma unroll
            for (int i2 = 0; i2 < 4; ++i2)
                a4[i2] = *(const float4*)&As[tm * 4 + i2][s0];
            #pragma unroll
            for (int ss = 0; ss < 4; ++ss)
                b4[ss] = *(const float4*)&Ws[s0 + ss][tn * 4];
            #pragma unroll
            for (int i2 = 0; i2 < 4; ++i2) {
                const float* av = (const float*)&a4[i2];
                #pragma unroll
                for (int ss = 0; ss < 4; ++ss) {
                    float a = av[ss];
                    acc[i2][0] += a * b4[ss].x;
                    acc[i2][1] += a * b4[ss].y;
                    acc[i2][2] += a * b4[ss].z;
                    acc[i2][3] += a * b4[ss].w;
                }
            }
        }
        __syncthreads();
    }

    // ---- epilogue: out[b, oc, r], contiguous in r -> float4 stores ----
    float* outb = out + (size_t)b * 512 * 1024;
    const int r_base = r0 + tm * 4;
    #pragma unroll
    for (int j = 0; j < 4; ++j) {
        int oc = p * 64 + tn * 4 + j;
        float4 v = make_float4(acc[0][j], acc[1][j], acc[2][j], acc[3][j]);
        *(float4*)&outb[(size_t)oc * 1024 + r_base] = v;
    }
}

extern "C" void kernel_launch(void* const* d_in, const int* in_sizes, int n_in,
                              void* d_out, int out_size, void* d_ws, size_t ws_size,
                              hipStream_t stream) {
    const float* x = (const float*)d_in[0];   // 8*256*32*32 fp32
    const float* w = (const float*)d_in[1];   // 8*36*64 fp32
    float* out = (float*)d_out;               // 8*512*32*32 fp32

    dim3 grid(PB, (N_BATCH * 1024) / 64);     // (8, 128)
    bcc_gemm_f32<<<grid, 256, 0, stream>>>(x, w, out);
}

// Round 2
// 134.092 us; speedup vs baseline: 4.0845x; 4.0845x over previous
//
#include <hip/hip_runtime.h>
#include <hip/hip_bf16.h>

// Block-circulant conv == GEMM  out[b,oc,r] = sum_k A[b*1024+r, k] * B[k, oc]
//   A[m,k]  = im2col(x) flattened per batch, reshaped (1024, 2304) contiguously
//             (the reference's quirky reshape makes A a contiguous view!)
//   B[k,oc] = w[oc>>6][k>>6][((oc&63)-(k&63))&63]  (circulant expansion)
//
// 3 dispatches: im2col->bf16 (ws), circulant-expand->bf16 (ws),
// then m97-style MFMA GEMM (128x128 tile, BK=64, global_load_lds width=16).
// Host-side fallback to the round-1 fp32 kernel if ws_size is too small.

#define QK 2304
#define MROWS 8192
#define NOC 512
#define QB 36

typedef __attribute__((ext_vector_type(8))) short short8;
typedef __attribute__((ext_vector_type(4))) float floatx4;

__device__ __forceinline__ ushort f2bf(float f) {
    __hip_bfloat16 h = __float2bfloat16(f);
    return *reinterpret_cast<ushort*>(&h);
}

__device__ __forceinline__ void async16(const void* g, void* l) {
    __builtin_amdgcn_global_load_lds((const __attribute__((address_space(1))) void*)g,
                                     (__attribute__((address_space(3))) void*)l, 16, 0, 0);
}

// ---------------- pre-kernel 1: im2col + bf16 cast ----------------
// wsA[m][k], m = b*1024 + r
__global__ __launch_bounds__(256) void im2col_bf16(const float* __restrict__ x,
                                                   ushort* __restrict__ wsA) {
    const int m = blockIdx.x;           // 0..8191
    const int b = m >> 10, r = m & 1023;
    const float* xb = x + (size_t)b * (256 * 32 * 32);
    ushort* row = wsA + (size_t)m * QK;
    for (int k0 = threadIdx.x * 2; k0 < QK; k0 += 512) {
        ushort u[2];
        #pragma unroll
        for (int e = 0; e < 2; ++e) {
            int k = k0 + e;
            int j = r * QK + k;
            int feat = j >> 10, loc = j & 1023;
            int c = feat / 9, kk = feat - c * 9;
            int di = kk / 3, dj = kk - di * 3;
            int hi = (loc >> 5) + di - 1, wi = (loc & 31) + dj - 1;
            float v = 0.f;
            if ((unsigned)hi < 32u && (unsigned)wi < 32u)
                v = xb[(c * 32 + hi) * 32 + wi];
            u[e] = f2bf(v);
        }
        *(ushort2*)&row[k0] = make_ushort2(u[0], u[1]);
    }
}

// ---------------- pre-kernel 2: circulant expand + bf16 ----------------
// wsB[n][k] (n-major so GEMM B-frags are k-contiguous)
__global__ __launch_bounds__(256) void expand_Bc(const float* __restrict__ w,
                                                 ushort* __restrict__ wsB) {
    const int n = blockIdx.x;           // 0..511
    const int p = n >> 6, t = n & 63;
    ushort* row = wsB + (size_t)n * QK;
    for (int k0 = threadIdx.x * 2; k0 < QK; k0 += 512) {
        ushort u[2];
        #pragma unroll
        for (int e = 0; e < 2; ++e) {
            int k = k0 + e;
            int q = k >> 6, s = k & 63;
            u[e] = f2bf(w[(p * QB + q) * 64 + ((t - s) & 63)]);
        }
        *(ushort2*)&row[k0] = make_ushort2(u[0], u[1]);
    }
}

// ---------------- main GEMM: 128x128 tile, BK=64, 8 waves ----------------
__global__ __launch_bounds__(512) void bcc_mfma(const ushort* __restrict__ A,
                                                const ushort* __restrict__ Bm,
                                                float* __restrict__ out) {
    __shared__ ushort As[128 * 64];   // [m][k] 16 KB
    __shared__ ushort Bs[128 * 64];   // [n][k] 16 KB
    const int tid = threadIdx.x;
    const int l  = tid & 63, w = tid >> 6;   // 8 waves
    const int wm = w >> 1,  wn = w & 1;      // 4 (m) x 2 (n) wave grid
    const int n0 = blockIdx.x * 128;
    const int m0 = blockIdx.y * 128;
    const int b  = m0 >> 10, r0 = m0 & 1023;

    floatx4 acc[4][2];   // [jn: n-frags][i: m-frags]
    #pragma unroll
    for (int jn = 0; jn < 4; ++jn)
        #pragma unroll
        for (int i = 0; i < 2; ++i) acc[jn][i] = (floatx4){0.f, 0.f, 0.f, 0.f};

    const int lrow  = l >> 3;        // 0..7
    const int lkoff = (l & 7) * 8;   // k offset 0..56

    for (int q = 0; q < QB; ++q) {
        const int kbase = q * 64;
        // stage 16 KB A + 16 KB B: 16 issues each, 2 per wave, 8 rows/issue
        #pragma unroll
        for (int t = 0; t < 2; ++t) {
            int row8 = w * 16 + t * 8;   // wave-uniform row base
            async16(A  + ((size_t)(m0 + row8 + lrow) * QK + kbase + lkoff),
                    &As[row8 * 64]);
            async16(Bm + ((size_t)(n0 + row8 + lrow) * QK + kbase + lkoff),
                    &Bs[row8 * 64]);
        }
        __syncthreads();

        #pragma unroll
        for (int ks = 0; ks < 2; ++ks) {
            short8 av[2], bv[4];
            #pragma unroll
            for (int i = 0; i < 2; ++i)
                av[i] = *(const short8*)&As[(wm * 32 + i * 16 + (l & 15)) * 64 + ks * 32 + (l >> 4) * 8];
            #pragma unroll
            for (int jn = 0; jn < 4; ++jn)
                bv[jn] = *(const short8*)&Bs[(wn * 64 + jn * 16 + (l & 15)) * 64 + ks * 32 + (l >> 4) * 8];
            // operand-swapped: D[row=oc][col=r] so stores are r-contiguous
            #pragma unroll
            for (int jn = 0; jn < 4; ++jn)
                #pragma unroll
                for (int i = 0; i < 2; ++i)
                    acc[jn][i] = __builtin_amdgcn_mfma_f32_16x16x32_bf16(bv[jn], av[i], acc[jn][i], 0, 0, 0);
        }
        __syncthreads();
    }

    // epilogue: out[b][oc][r]; 16-lane groups cover 64B-contiguous r
    #pragma unroll
    for (int jn = 0; jn < 4; ++jn) {
        #pragma unroll
        for (int i = 0; i < 2; ++i) {
            int rr = r0 + wm * 32 + i * 16 + (l & 15);
            #pragma unroll
            for (int e = 0; e < 4; ++e) {
                int oc = n0 + wn * 64 + jn * 16 + (l >> 4) * 4 + e;
                out[((size_t)b * NOC + oc) * 1024 + rr] = acc[jn][i][e];
            }
        }
    }
}

// ---------------- round-1 fp32 fallback (ws too small) ----------------
__global__ __launch_bounds__(256) void bcc_gemm_f32(
    const float* __restrict__ x, const float* __restrict__ w,
    float* __restrict__ out) {
    __shared__ float Asf[64][68];
    __shared__ float Wsf[64][68];
    const int tid = threadIdx.x;
    const int tn = tid & 15, tm = tid >> 4;
    const int p = blockIdx.x;
    const int m0 = blockIdx.y * 64;
    const int b = m0 >> 10, r0 = m0 & 1023;
    const float* xb = x + (size_t)b * (256 * 32 * 32);
    float acc[4][4] = {};
    for (int q = 0; q < QB; ++q) {
        #pragma unroll
        for (int i = 0; i < 16; ++i) {
            int idx = i * 256 + tid;
            int s = idx & 63, mm = idx >> 6;
            int flat = (r0 + mm) * QK + q * 64 + s;
            int feat = flat >> 10, loc = flat & 1023;
            int c = feat / 9, kk = feat - c * 9;
            int hi = (loc >> 5) + (kk / 3) - 1;
            int wi = (loc & 31) + (kk % 3) - 1;
            float v = 0.0f;
            if ((unsigned)hi < 32u && (unsigned)wi < 32u)
                v = xb[(c * 32 + hi) * 32 + wi];
            Asf[mm][s] = v;
        }
        const float* wb = w + (p * QB + q) * 64;
        #pragma unroll
        for (int i = 0; i < 16; ++i) {
            int idx = i * 256 + tid;
            int t = idx & 63, s = idx >> 6;
            Wsf[s][t] = wb[(t - s) & 63];
        }
        __syncthreads();
        #pragma unroll
        for (int s0 = 0; s0 < 64; s0 += 4) {
            float4 a4[4], b4[4];
            #pragma unroll
            for (int i2 = 0; i2 < 4; ++i2)
                a4[i2] = *(const float4*)&Asf[tm * 4 + i2][s0];
            #pragma unroll
            for (int ss = 0; ss < 4; ++ss)
                b4[ss] = *(const float4*)&Wsf[s0 + ss][tn * 4];
            #pragma unroll
            for (int i2 = 0; i2 < 4; ++i2) {
                const float* av = (const float*)&a4[i2];
                #pragma unroll
                for (int ss = 0; ss < 4; ++ss) {
                    float a = av[ss];
                    acc[i2][0] += a * b4[ss].x;
                    acc[i2][1] += a * b4[ss].y;
                    acc[i2][2] += a * b4[ss].z;
                    acc[i2][3] += a * b4[ss].w;
                }
            }
        }
        __syncthreads();
    }
    float* outb = out + (size_t)b * NOC * 1024;
    const int r_base = r0 + tm * 4;
    #pragma unroll
    for (int j = 0; j < 4; ++j) {
        int oc = p * 64 + tn * 4 + j;
        float4 v = make_float4(acc[0][j], acc[1][j], acc[2][j], acc[3][j]);
        *(float4*)&outb[(size_t)oc * 1024 + r_base] = v;
    }
}

extern "C" void kernel_launch(void* const* d_in, const int* in_sizes, int n_in,
                              void* d_out, int out_size, void* d_ws, size_t ws_size,
                              hipStream_t stream) {
    const float* x = (const float*)d_in[0];
    const float* w = (const float*)d_in[1];
    float* out = (float*)d_out;

    const size_t bytesA = (size_t)MROWS * QK * sizeof(ushort);  // 37,748,736
    const size_t bytesB = (size_t)NOC * QK * sizeof(ushort);    //  2,359,296

    if (ws_size >= bytesA + bytesB) {
        ushort* wsA = (ushort*)d_ws;
        ushort* wsB = (ushort*)((char*)d_ws + bytesA);
        im2col_bf16<<<MROWS, 256, 0, stream>>>(x, wsA);
        expand_Bc<<<NOC, 256, 0, stream>>>(w, wsB);
        bcc_mfma<<<dim3(NOC / 128, MROWS / 128), 512, 0, stream>>>(wsA, wsB, out);
    } else {
        bcc_gemm_f32<<<dim3(8, MROWS / 64), 256, 0, stream>>>(x, w, out);
    }
}